// Round 3
// baseline (3596.807 us; speedup 1.0000x reference)
//
#include <hip/hip_runtime.h>

// GraphProject: out[b,n,:] = [xyz(3) | bilerp(feat0,64) | bilerp(feat1,128)
//                             | bilerp(feat2,256) | bilerp(feat3,512)]  (963 ch)
// proj_mat unused by the reference.
//
// Structure: ~93% of (vertex,scale) bilinear blocks are EXACTLY zero (any
// clamped/integral coordinate zeroes all four weights; h/w are Cauchy with
// P(interior) ~ 0.27 per axis). So:
//   1) zero_fill: nontemporal vec4 stream-zero of the whole 3.08 GB output
//      (770,400,000 dwords = 192,600,000 vec4 exactly, no tail) — runs at
//      the pure-write roofline.
//   2) gp_sparse: one wave per vertex (grid-stride). Writes xyz; for the ~7%
//      nonzero (v,sc) blocks does the channel-last coalesced gather + store.
//      No LDS, no syncthreads.
// Transpose prepass kept: makes the sparse gathers lane-contiguous.

typedef float floatx4 __attribute__((ext_vector_type(4)));  // native vec type
                                                            // (HIP float4 class
                                                            // rejected by
                                                            // __builtin_nontemporal_store)

// ---- prepass: (B,C,S,S) -> (B,S,S,C) channel-last for coalesced gathers ----
template<int C, int S>
__global__ __launch_bounds__(256) void transpose_feat(const float* __restrict__ src,
                                                      float* __restrict__ dst,
                                                      int total) {
    int i = blockIdx.x * 256 + threadIdx.x;
    if (i >= total) return;
    int c  = i % C;
    int p  = i / C;
    int w  = p % S;
    int p2 = p / S;
    int h  = p2 % S;
    int b  = p2 / S;
    dst[i] = src[((b * C + c) * S + h) * S + w];
}

// ---- 1) stream-zero the output at max write BW ----
__global__ __launch_bounds__(256) void zero_fill(floatx4* __restrict__ out4,
                                                 long long n4) {
    long long i      = (long long)blockIdx.x * 256 + threadIdx.x;
    long long stride = (long long)gridDim.x * 256;
    const floatx4 z = {0.0f, 0.0f, 0.0f, 0.0f};
    for (; i < n4; i += stride)
        __builtin_nontemporal_store(z, &out4[i]);
}

// ---- 2) sparse pass: one wave per vertex, write xyz + nonzero blocks ----
__global__ __launch_bounds__(256) void gp_sparse(const float* __restrict__ verts,
                                                 const float* __restrict__ f0,
                                                 const float* __restrict__ f1,
                                                 const float* __restrict__ f2,
                                                 const float* __restrict__ f3,
                                                 float* __restrict__ out,
                                                 int N, int total_v) {
    const int lane    = threadIdx.x & 63;
    const int wave_id = (int)((blockIdx.x * 256 + threadIdx.x) >> 6);
    const int nwaves  = (int)((gridDim.x * 256) >> 6);

    const int   Sarr[4] = {56, 28, 14, 7};
    const int   Carr[4] = {64, 128, 256, 512};
    const float invA[4] = {0.25f, 0.125f, 0.0625f, 0.03125f};
    const int   Kb[4]   = {3, 67, 195, 451};
    const float* fps[4] = {f0, f1, f2, f3};

    for (int vi = wave_id; vi < total_v; vi += nwaves) {
        const int b = vi / N;
        // wave-uniform loads (all lanes same address -> single line)
        const float X = verts[3 * vi + 0];
        const float Y = verts[3 * vi + 1];
        const float Z = verts[3 * vi + 2];
        const size_t obase = (size_t)vi * 963;

        // xyz passthrough
        const float v3 = (lane == 0) ? X : ((lane == 1) ? Y : Z);
        if (lane < 3) out[obase + lane] = v3;

        // h = FY*(Y/Z)+CY ; w = FX*(X/-Z)+CX  -- exact rn ops, no contraction
        const float h = __fadd_rn(__fmul_rn(250.0f, __fdiv_rn(Y, Z)), 112.0f);
        const float w = __fadd_rn(__fmul_rn(250.0f, __fdiv_rn(X, -Z)), 112.0f);

#pragma unroll
        for (int sc = 0; sc < 4; ++sc) {
            const int   s    = Sarr[sc];
            const int   C    = Carr[sc];
            const float smax = (float)(s - 1);

            const float x = fminf(fmaxf(__fmul_rn(h, invA[sc]), 0.0f), smax);
            const float y = fminf(fmaxf(__fmul_rn(w, invA[sc]), 0.0f), smax);
            const float x1f = floorf(x), x2f = ceilf(x);
            const float y1f = floorf(y), y2f = ceilf(y);

            // all four weights have both an x- and a y-factor: if either
            // coordinate is integral (incl. any clamp), block is exactly 0
            // and zero_fill already wrote it.
            if (x1f != x2f && y1f != y2f) {
                const int x1 = (int)x1f, x2 = (int)x2f;
                const int y1 = (int)y1f, y2 = (int)y2f;
                const float w11 = (x2f - x) * (y2f - y);
                const float w12 = (x2f - x) * (y - y1f);
                const float w21 = (x - x1f) * (y2f - y);
                const float w22 = (x - x1f) * (y - y1f);

                const int base = b * s * s;
                const int o11 = (base + x1 * s + y1) * C;
                const int o12 = (base + x1 * s + y2) * C;
                const int o21 = (base + x2 * s + y1) * C;
                const int o22 = (base + x2 * s + y2) * C;
                const float* __restrict__ fp = fps[sc];
                float* __restrict__ op = out + obase + Kb[sc];

                for (int c = lane; c < C; c += 64) {
                    // ref order: w11*Q11 + w21*Q21 + w12*Q12 + w22*Q22
                    const float r = w11 * fp[o11 + c] + w21 * fp[o21 + c]
                                  + w12 * fp[o12 + c] + w22 * fp[o22 + c];
                    __builtin_nontemporal_store(r, op + c);
                }
            }
        }
    }
}

extern "C" void kernel_launch(void* const* d_in, const int* in_sizes, int n_in,
                              void* d_out, int out_size, void* d_ws, size_t ws_size,
                              hipStream_t stream) {
    const float* verts = (const float*)d_in[0];
    const float* f0s   = (const float*)d_in[1];
    const float* f1s   = (const float*)d_in[2];
    const float* f2s   = (const float*)d_in[3];
    const float* f3s   = (const float*)d_in[4];
    // d_in[5] (proj_mat) unused by reference

    const int B = in_sizes[5] / 16;          // proj is B*4*4
    const int N = in_sizes[0] / (3 * B);
    const int total_v = B * N;

    const int n0 = B * 64 * 56 * 56;
    const int n1 = B * 128 * 28 * 28;
    const int n2 = B * 256 * 14 * 14;
    const int n3 = B * 512 * 7 * 7;

    float* t0 = (float*)d_ws;
    float* t1 = t0 + n0;
    float* t2 = t1 + n1;
    float* t3 = t2 + n2;

    transpose_feat<64, 56><<<(n0 + 255) / 256, 256, 0, stream>>>(f0s, t0, n0);
    transpose_feat<128, 28><<<(n1 + 255) / 256, 256, 0, stream>>>(f1s, t1, n1);
    transpose_feat<256, 14><<<(n2 + 255) / 256, 256, 0, stream>>>(f2s, t2, n2);
    transpose_feat<512, 7><<<(n3 + 255) / 256, 256, 0, stream>>>(f3s, t3, n3);

    // 1) stream-zero the whole output (770,400,000 dwords = 192,600,000 x vec4)
    const long long n4 = ((long long)total_v * 963) / 4;
    zero_fill<<<4096, 256, 0, stream>>>((floatx4*)d_out, n4);

    // 2) sparse gather pass: one wave per vertex, grid-stride
    gp_sparse<<<2048, 256, 0, stream>>>(verts, t0, t1, t2, t3,
                                        (float*)d_out, N, total_v);
}